// Round 1
// baseline (29900.369 us; speedup 1.0000x reference)
//
#include <hip/hip_runtime.h>
#include <hip/hip_bf16.h>
#include <hip/hip_fp16.h>

// Problem constants
#define BB 64
#define SS 512
#define HH 512
#define EE 512
#define CC 2

typedef _Float16 h2 __attribute__((ext_vector_type(2)));

static __device__ inline float dot2f(h2 a, h2 b, float c) {
#if __has_builtin(__builtin_amdgcn_fdot2)
  return __builtin_amdgcn_fdot2(a, b, c, false);
#else
  return c + (float)a[0] * (float)b[0] + (float)a[1] * (float)b[1];
#endif
}

// out[m][n] = sum_k A[m][k] * W[n][k] + bias0[n] + bias1[n]
// GATHER: A row m comes from emb[tokens[m]]
template <bool GATHER>
__global__ __launch_bounds__(256) void gemm_bias(
    const float* __restrict__ Aden, const int* __restrict__ tokens,
    const float* __restrict__ emb, const float* __restrict__ W,
    const float* __restrict__ bias0, const float* __restrict__ bias1,
    float* __restrict__ out, int M, int N, int K) {
  __shared__ float As[16][65];
  __shared__ float Bs[16][65];
  const int tx = threadIdx.x;  // 0..15
  const int ty = threadIdx.y;  // 0..15
  const int bm = blockIdx.y * 64;
  const int bn = blockIdx.x * 64;
  float acc[4][4] = {};

  for (int k0 = 0; k0 < K; k0 += 16) {
    // Load A tile: 64 rows x 16 k-cols.  thread (tx,ty): k = k0+tx, row = bm + p*16 + ty
#pragma unroll
    for (int p = 0; p < 4; ++p) {
      const int m = bm + p * 16 + ty;
      const float* arow;
      if constexpr (GATHER) {
        arow = emb + (long)tokens[m] * EE;
      } else {
        arow = Aden + (long)m * K;
      }
      As[tx][p * 16 + ty] = arow[k0 + tx];
    }
    // Load B tile: Bs[k][n] = W[bn+n][k0+k]
#pragma unroll
    for (int p = 0; p < 4; ++p) {
      const int n = bn + p * 16 + ty;
      Bs[tx][p * 16 + ty] = W[(long)n * K + k0 + tx];
    }
    __syncthreads();
#pragma unroll
    for (int k = 0; k < 16; ++k) {
      float a[4], bb[4];
#pragma unroll
      for (int i = 0; i < 4; ++i) a[i] = As[k][ty * 4 + i];
#pragma unroll
      for (int j = 0; j < 4; ++j) bb[j] = Bs[k][tx * 4 + j];
#pragma unroll
      for (int i = 0; i < 4; ++i)
#pragma unroll
        for (int j = 0; j < 4; ++j) acc[i][j] += a[i] * bb[j];
    }
    __syncthreads();
  }
#pragma unroll
  for (int i = 0; i < 4; ++i) {
    const int m = bm + ty * 4 + i;
#pragma unroll
    for (int j = 0; j < 4; ++j) {
      const int n = bn + tx * 4 + j;
      out[(long)m * N + n] = acc[i][j] + bias0[n] + bias1[n];
    }
  }
}

// Recurrence for one layer: h_t = tanh(xw_t + W_hh h_{t-1}).
// 4 workgroups per batch element; wg owns 128 output rows; W slice in VGPRs (f16).
// h exchange through hout + per-(b,t) flag counters.
__global__ __launch_bounds__(256) void rec_layer(
    const float* __restrict__ Whh,   // [512][512] f32
    const float* __restrict__ xw,    // [B*S][512] f32 (input part + biases)
    float* __restrict__ hout,        // [B*S][512] f32 (layer output + exchange)
    unsigned int* __restrict__ flags  // [B][S] counters (pre-zeroed)
) {
  const int b = blockIdx.x >> 2;
  const int chunk = blockIdx.x & 3;
  const int tid = threadIdx.x;
  const int r = tid >> 1;    // local row 0..127
  const int sel = tid & 1;   // which half of k
  const int row = chunk * 128 + r;

  __shared__ h2 hs[256];  // h_{t-1} as half2 (512 f16)

  // Load W slice into registers: row `row`, cols [sel*256, sel*256+256) as 128 half2
  h2 w[128];
  {
    const float4* wrow = (const float4*)(Whh + (long)row * HH + sel * 256);
#pragma unroll
    for (int q = 0; q < 64; ++q) {
      float4 v = wrow[q];
      h2 a, bq;
      a[0] = (_Float16)v.x; a[1] = (_Float16)v.y;
      bq[0] = (_Float16)v.z; bq[1] = (_Float16)v.w;
      w[2 * q] = a;
      w[2 * q + 1] = bq;
    }
  }

  for (int t = 0; t < SS; ++t) {
    if (t == 0) {
      h2 z; z[0] = (_Float16)0.f; z[1] = (_Float16)0.f;
      hs[tid] = z;
    } else {
      // wait until all 4 chunks of h_{t-1} for this b are published
      while (__hip_atomic_load(&flags[b * SS + t - 1], __ATOMIC_ACQUIRE,
                               __HIP_MEMORY_SCOPE_AGENT) < 4u) {
        __builtin_amdgcn_s_sleep(1);
      }
      float2 hv = ((const float2*)(hout + (long)(b * SS + t - 1) * HH))[tid];
      h2 v; v[0] = (_Float16)hv.x; v[1] = (_Float16)hv.y;
      hs[tid] = v;
    }
    __syncthreads();

    float s0 = 0.f, s1 = 0.f, s2 = 0.f, s3 = 0.f;
    const h2* hp = hs + sel * 128;
#pragma unroll
    for (int q = 0; q < 128; q += 4) {
      s0 = dot2f(w[q + 0], hp[q + 0], s0);
      s1 = dot2f(w[q + 1], hp[q + 1], s1);
      s2 = dot2f(w[q + 2], hp[q + 2], s2);
      s3 = dot2f(w[q + 3], hp[q + 3], s3);
    }
    float p = (s0 + s1) + (s2 + s3);
    p += __shfl_xor(p, 1);

    if (sel == 0) {
      const long o = (long)(b * SS + t) * HH + row;
      hout[o] = tanhf(xw[o] + p);
    }
    __threadfence();      // make h stores visible (agent scope) before flag
    __syncthreads();      // all threads' stores done
    if (tid == 0) {
      atomicAdd(&flags[b * SS + t], 1u);
    }
    __syncthreads();
  }
}

// out[m][c] = sum_h h1[m][h] * Wfc[c][h] + bfc[c];  one wave per row m
__global__ __launch_bounds__(256) void fc_kernel(
    const float* __restrict__ h1, const float* __restrict__ Wfc,
    const float* __restrict__ bfc, float* __restrict__ out) {
  const int lane = threadIdx.x & 63;
  const int wid = threadIdx.x >> 6;
  const long m = (long)blockIdx.x * 4 + wid;
  const float4* hrow = (const float4*)(h1 + m * HH);
  const float4* w0 = (const float4*)(Wfc);
  const float4* w1 = (const float4*)(Wfc + HH);
  float p0 = 0.f, p1 = 0.f;
#pragma unroll
  for (int q = 0; q < 2; ++q) {
    const int idx = lane * 2 + q;
    float4 hv = hrow[idx];
    float4 a = w0[idx];
    float4 bq = w1[idx];
    p0 += hv.x * a.x + hv.y * a.y + hv.z * a.z + hv.w * a.w;
    p1 += hv.x * bq.x + hv.y * bq.y + hv.z * bq.z + hv.w * bq.w;
  }
#pragma unroll
  for (int off = 32; off; off >>= 1) {
    p0 += __shfl_down(p0, off);
    p1 += __shfl_down(p1, off);
  }
  if (lane == 0) {
    out[m * 2 + 0] = p0 + bfc[0];
    out[m * 2 + 1] = p1 + bfc[1];
  }
}

extern "C" void kernel_launch(void* const* d_in, const int* in_sizes, int n_in,
                              void* d_out, int out_size, void* d_ws, size_t ws_size,
                              hipStream_t stream) {
  const int* tokens = (const int*)d_in[0];
  const float* emb = (const float*)d_in[1];
  const float* W_ih0 = (const float*)d_in[2];
  const float* b_ih0 = (const float*)d_in[3];
  const float* W_hh0 = (const float*)d_in[4];
  const float* b_hh0 = (const float*)d_in[5];
  const float* W_ih1 = (const float*)d_in[6];
  const float* b_ih1 = (const float*)d_in[7];
  const float* W_hh1 = (const float*)d_in[8];
  const float* b_hh1 = (const float*)d_in[9];
  const float* W_fc = (const float*)d_in[10];
  const float* b_fc = (const float*)d_in[11];
  float* out = (float*)d_out;

  const long MS = (long)BB * SS;  // 32768
  float* bufA = (float*)d_ws;            // xw buffer  [MS][512]
  float* bufB = bufA + MS * HH;          // h buffer   [MS][512]
  unsigned int* flags0 = (unsigned int*)(bufB + MS * HH);
  unsigned int* flags1 = flags0 + BB * SS;

  hipMemsetAsync(flags0, 0, 2 * BB * SS * sizeof(unsigned int), stream);

  dim3 gb(16, 16);
  // xw0 = gather(emb, tokens) @ W_ih0^T + b_ih0 + b_hh0
  gemm_bias<true><<<dim3(8, 512), gb, 0, stream>>>(
      nullptr, tokens, emb, W_ih0, b_ih0, b_hh0, bufA, (int)MS, HH, EE);
  // layer 0 recurrence -> h0 in bufB
  rec_layer<<<256, 256, 0, stream>>>(W_hh0, bufA, bufB, flags0);
  // xw1 = h0 @ W_ih1^T + b_ih1 + b_hh1
  gemm_bias<false><<<dim3(8, 512), gb, 0, stream>>>(
      bufB, nullptr, nullptr, W_ih1, b_ih1, b_hh1, bufA, (int)MS, HH, HH);
  // layer 1 recurrence -> h1 in bufB
  rec_layer<<<256, 256, 0, stream>>>(W_hh1, bufA, bufB, flags1);
  // FC
  fc_kernel<<<8192, 256, 0, stream>>>(bufB, W_fc, b_fc, out);
}

// Round 2
// 2314.888 us; speedup vs baseline: 12.9165x; 12.9165x over previous
//
#include <hip/hip_runtime.h>
#include <hip/hip_bf16.h>
#include <hip/hip_fp16.h>

// Problem constants
#define BB 64
#define SS 512
#define HH 512
#define EE 512
#define CC 2

typedef _Float16 h2 __attribute__((ext_vector_type(2)));
typedef _Float16 h8 __attribute__((ext_vector_type(8)));

#define PICK(v, I) (__builtin_shufflevector((v), (v), 2 * (I), 2 * (I) + 1))

static __device__ inline float dot2f(h2 a, h2 b, float c) {
#if __has_builtin(__builtin_amdgcn_fdot2)
  return __builtin_amdgcn_fdot2(a, b, c, false);
#else
  return c + (float)a[0] * (float)b[0] + (float)a[1] * (float)b[1];
#endif
}

static __device__ inline float tanhf_fast(float x) {
  float e = __expf(2.0f * x);
#if __has_builtin(__builtin_amdgcn_rcpf)
  return 1.0f - 2.0f * __builtin_amdgcn_rcpf(e + 1.0f);
#else
  return 1.0f - 2.0f / (e + 1.0f);
#endif
}

// out[m][n] = sum_k A[m][k] * W[n][k] + bias0[n] + bias1[n]
// GATHER: A row m comes from emb[tokens[m]]
template <bool GATHER>
__global__ __launch_bounds__(256) void gemm_bias(
    const float* __restrict__ Aden, const int* __restrict__ tokens,
    const float* __restrict__ emb, const float* __restrict__ W,
    const float* __restrict__ bias0, const float* __restrict__ bias1,
    float* __restrict__ out, int M, int N, int K) {
  __shared__ float As[16][65];
  __shared__ float Bs[16][65];
  const int tx = threadIdx.x;  // 0..15
  const int ty = threadIdx.y;  // 0..15
  const int bm = blockIdx.y * 64;
  const int bn = blockIdx.x * 64;
  float acc[4][4] = {};

  for (int k0 = 0; k0 < K; k0 += 16) {
#pragma unroll
    for (int p = 0; p < 4; ++p) {
      const int m = bm + p * 16 + ty;
      const float* arow;
      if constexpr (GATHER) {
        arow = emb + (long)tokens[m] * EE;
      } else {
        arow = Aden + (long)m * K;
      }
      As[tx][p * 16 + ty] = arow[k0 + tx];
    }
#pragma unroll
    for (int p = 0; p < 4; ++p) {
      const int n = bn + p * 16 + ty;
      Bs[tx][p * 16 + ty] = W[(long)n * K + k0 + tx];
    }
    __syncthreads();
#pragma unroll
    for (int k = 0; k < 16; ++k) {
      float a[4], bb[4];
#pragma unroll
      for (int i = 0; i < 4; ++i) a[i] = As[k][ty * 4 + i];
#pragma unroll
      for (int j = 0; j < 4; ++j) bb[j] = Bs[k][tx * 4 + j];
#pragma unroll
      for (int i = 0; i < 4; ++i)
#pragma unroll
        for (int j = 0; j < 4; ++j) acc[i][j] += a[i] * bb[j];
    }
    __syncthreads();
  }
#pragma unroll
  for (int i = 0; i < 4; ++i) {
    const int m = bm + ty * 4 + i;
#pragma unroll
    for (int j = 0; j < 4; ++j) {
      const int n = bn + tx * 4 + j;
      out[(long)m * N + n] = acc[i][j] + bias0[n] + bias1[n];
    }
  }
}

// Recurrence, one workgroup per batch element. 512 threads = 1 thread per
// output row. W_hh row r: cols 0..383 as f16 in 192 VGPR h2's; cols 384..511
// as 16 h8 chunks in LDS (conflict-free tid*16B stride). h_{t-1} double-
// buffered in LDS (f16); exactly one __syncthreads per step, no global sync.
__global__ __launch_bounds__(512, 2) void rec_layer(
    const float* __restrict__ Whh,  // [512][512] f32
    const float* __restrict__ xw,   // [B*S][512] f32 (input part + biases)
    float* __restrict__ hout        // [B*S][512] f32
) {
  extern __shared__ char smem[];
  h8* wlds = (h8*)smem;                              // 16*512 h8 = 128 KB
  _Float16* hsbuf = (_Float16*)(smem + 16 * 512 * 16);  // 2*512 f16 = 2 KB

  const int b = blockIdx.x;
  const int tid = threadIdx.x;
  const int r = tid;  // output row
  const long base = (long)b * SS;

  // ---- setup: load W row r ----
  h2 w[192];
  {
    const float2* wrow2 = (const float2*)(Whh + (long)r * HH);
#pragma unroll
    for (int q = 0; q < 192; ++q) {
      float2 f = wrow2[q];
      h2 v;
      v[0] = (_Float16)f.x;
      v[1] = (_Float16)f.y;
      w[q] = v;
    }
    const float4* wrow4 = (const float4*)(Whh + (long)r * HH);
#pragma unroll
    for (int j = 0; j < 16; ++j) {
      float4 a = wrow4[2 * (48 + j)];
      float4 c = wrow4[2 * (48 + j) + 1];
      h8 v = {(_Float16)a.x, (_Float16)a.y, (_Float16)a.z, (_Float16)a.w,
              (_Float16)c.x, (_Float16)c.y, (_Float16)c.z, (_Float16)c.w};
      wlds[j * 512 + tid] = v;
    }
  }
  hsbuf[tid] = (_Float16)0.f;  // h_{-1} = 0 (buffer 0)
  __syncthreads();

  for (int t = 0; t < SS; ++t) {
    const h8* hc8 = (const h8*)(hsbuf + (t & 1) * 512);
    const float xwv = xw[(base + t) * HH + r];

    float a0 = 0.f, a1 = 0.f, a2 = 0.f, a3 = 0.f;
#pragma unroll
    for (int j = 0; j < 48; ++j) {
      h8 hv = hc8[j];
      a0 = dot2f(w[4 * j + 0], PICK(hv, 0), a0);
      a1 = dot2f(w[4 * j + 1], PICK(hv, 1), a1);
      a2 = dot2f(w[4 * j + 2], PICK(hv, 2), a2);
      a3 = dot2f(w[4 * j + 3], PICK(hv, 3), a3);
    }
#pragma unroll
    for (int j = 0; j < 16; ++j) {
      h8 wv = wlds[j * 512 + tid];
      h8 hv = hc8[48 + j];
      a0 = dot2f(PICK(wv, 0), PICK(hv, 0), a0);
      a1 = dot2f(PICK(wv, 1), PICK(hv, 1), a1);
      a2 = dot2f(PICK(wv, 2), PICK(hv, 2), a2);
      a3 = dot2f(PICK(wv, 3), PICK(hv, 3), a3);
    }
    float p = (a0 + a1) + (a2 + a3);
    float hval = tanhf_fast(xwv + p);

    hsbuf[((t + 1) & 1) * 512 + r] = (_Float16)hval;
    hout[(base + t) * HH + r] = hval;
    __syncthreads();
  }
}

// out[m][c] = sum_h h1[m][h] * Wfc[c][h] + bfc[c];  one wave per row m
__global__ __launch_bounds__(256) void fc_kernel(
    const float* __restrict__ h1, const float* __restrict__ Wfc,
    const float* __restrict__ bfc, float* __restrict__ out) {
  const int lane = threadIdx.x & 63;
  const int wid = threadIdx.x >> 6;
  const long m = (long)blockIdx.x * 4 + wid;
  const float4* hrow = (const float4*)(h1 + m * HH);
  const float4* w0 = (const float4*)(Wfc);
  const float4* w1 = (const float4*)(Wfc + HH);
  float p0 = 0.f, p1 = 0.f;
#pragma unroll
  for (int q = 0; q < 2; ++q) {
    const int idx = lane * 2 + q;
    float4 hv = hrow[idx];
    float4 a = w0[idx];
    float4 bq = w1[idx];
    p0 += hv.x * a.x + hv.y * a.y + hv.z * a.z + hv.w * a.w;
    p1 += hv.x * bq.x + hv.y * bq.y + hv.z * bq.z + hv.w * bq.w;
  }
#pragma unroll
  for (int off = 32; off; off >>= 1) {
    p0 += __shfl_down(p0, off);
    p1 += __shfl_down(p1, off);
  }
  if (lane == 0) {
    out[m * 2 + 0] = p0 + bfc[0];
    out[m * 2 + 1] = p1 + bfc[1];
  }
}

extern "C" void kernel_launch(void* const* d_in, const int* in_sizes, int n_in,
                              void* d_out, int out_size, void* d_ws, size_t ws_size,
                              hipStream_t stream) {
  const int* tokens = (const int*)d_in[0];
  const float* emb = (const float*)d_in[1];
  const float* W_ih0 = (const float*)d_in[2];
  const float* b_ih0 = (const float*)d_in[3];
  const float* W_hh0 = (const float*)d_in[4];
  const float* b_hh0 = (const float*)d_in[5];
  const float* W_ih1 = (const float*)d_in[6];
  const float* b_ih1 = (const float*)d_in[7];
  const float* W_hh1 = (const float*)d_in[8];
  const float* b_hh1 = (const float*)d_in[9];
  const float* W_fc = (const float*)d_in[10];
  const float* b_fc = (const float*)d_in[11];
  float* out = (float*)d_out;

  const long MS = (long)BB * SS;  // 32768
  float* bufA = (float*)d_ws;     // xw buffer  [MS][512]
  float* bufB = bufA + MS * HH;   // h buffer   [MS][512]

  const int rec_lds = 16 * 512 * 16 + 2 * 512 * 2;  // 133120 B

  dim3 gb(16, 16);
  // xw0 = gather(emb, tokens) @ W_ih0^T + b_ih0 + b_hh0
  gemm_bias<true><<<dim3(8, 512), gb, 0, stream>>>(
      nullptr, tokens, emb, W_ih0, b_ih0, b_hh0, bufA, (int)MS, HH, EE);
  // layer 0 recurrence -> h0 in bufB
  rec_layer<<<64, 512, rec_lds, stream>>>(W_hh0, bufA, bufB);
  // xw1 = h0 @ W_ih1^T + b_ih1 + b_hh1
  gemm_bias<false><<<dim3(8, 512), gb, 0, stream>>>(
      bufB, nullptr, nullptr, W_ih1, b_ih1, b_hh1, bufA, (int)MS, HH, HH);
  // layer 1 recurrence -> h1 in bufB
  rec_layer<<<64, 512, rec_lds, stream>>>(W_hh1, bufA, bufB);
  // FC
  fc_kernel<<<8192, 256, 0, stream>>>(bufB, W_fc, b_fc, out);
}